// Round 3
// baseline (220.928 us; speedup 1.0000x reference)
//
#include <hip/hip_runtime.h>
#include <hip/hip_cooperative_groups.h>

namespace cg = cooperative_groups;

#define N_TOTAL 4194304   // 2048*256*8
#define B_SIZE  2048
#define L_SIZE  256
#define I_DIM   8
#define H       32
#define NBLK    512       // cooperative grid: each block owns 4 batch rows
#define SLOT    16        // 128B stride between per-block ws slots (doubles)
#define WS_LOSS 8192      // double index where loss slots start

#define AST(p, v) __hip_atomic_store((p), (v), __ATOMIC_RELAXED, __HIP_MEMORY_SCOPE_AGENT)
#define ALD(p)    __hip_atomic_load((p), __ATOMIC_RELAXED, __HIP_MEMORY_SCOPE_AGENT)

// Process one row held in registers xr[0..7] (per-thread position t).
#define PROC_ROW(xr, yidx)                                                    \
    {                                                                         \
        float sc_ = cst[8];                                                   \
        _Pragma("unroll")                                                     \
        for (int i_ = 0; i_ < 8; i_++) sc_ += xr[i_] * cst[i_];               \
        float m_ = sc_;                                                       \
        for (int off_ = 32; off_; off_ >>= 1)                                 \
            m_ = fmaxf(m_, __shfl_down(m_, off_));                            \
        if (lane == 0) wmax[wid] = m_;                                        \
        __syncthreads();                                                      \
        m_ = fmaxf(fmaxf(wmax[0], wmax[1]), fmaxf(wmax[2], wmax[3]));         \
        m_ = fmaxf(m_, cst[9]);                                               \
        float e_ = expf(sc_ - m_);                                            \
        float v_[9];                                                          \
        v_[0] = e_;                                                           \
        _Pragma("unroll")                                                     \
        for (int i_ = 0; i_ < 8; i_++) v_[i_ + 1] = e_ * xr[i_];              \
        for (int off_ = 32; off_; off_ >>= 1) {                               \
            _Pragma("unroll")                                                 \
            for (int j_ = 0; j_ < 9; j_++) v_[j_] += __shfl_down(v_[j_], off_);\
        }                                                                     \
        if (lane == 0) {                                                      \
            _Pragma("unroll")                                                 \
            for (int j_ = 0; j_ < 9; j_++) wsum[wid][j_] = v_[j_];            \
        }                                                                     \
        __syncthreads();                                                      \
        if (t == 0) {                                                         \
            float se_ = wsum[0][0] + wsum[1][0] + wsum[2][0] + wsum[3][0];    \
            float ecls_ = expf(cst[9] - m_);                                  \
            float inv_ = 1.f / (se_ + ecls_);                                 \
            float S256_ = ecls_ * inv_;                                       \
            float z_[2];                                                      \
            _Pragma("unroll")                                                 \
            for (int o_ = 0; o_ < 2; o_++) {                                  \
                float a_ = 0.f;                                               \
                _Pragma("unroll")                                             \
                for (int i_ = 0; i_ < 8; i_++) {                              \
                    float wi_ = (wsum[0][i_ + 1] + wsum[1][i_ + 1] +          \
                                 wsum[2][i_ + 1] + wsum[3][i_ + 1]) * inv_;   \
                    a_ += wi_ * cst[10 + i_ * 2 + o_];                        \
                }                                                             \
                z_[o_] = a_ + (1.f - S256_) * cst[26 + o_] +                  \
                         S256_ * cst[28 + o_] + cst[30 + o_];                 \
            }                                                                 \
            float zm_ = fmaxf(z_[0], z_[1]);                                  \
            float lse_ = zm_ + logf(expf(z_[0] - zm_) + expf(z_[1] - zm_));   \
            int yb_ = y[yidx];                                                \
            lossAcc += (double)(lse_ - z_[yb_]);                              \
        }                                                                     \
        __syncthreads();                                                      \
    }

// Shared constant-fold: fills cst[32] from the small weights + (mu, sdev).
__device__ __forceinline__ void fold_constants(
    int t, double mu, float sdev,
    const float* __restrict__ W1, const float* __restrict__ cls,
    const float* __restrict__ Wq, const float* __restrict__ Wk,
    const float* __restrict__ Wv, const float* __restrict__ Wt,
    const float* __restrict__ W2,
    float* qv, float* kcls, float* vcls, float* tv, float* gg,
    float (*WV)[H], float* cst)
{
    const float rs32 = 0.17677669529663687f;   // 1/sqrt(32)
    if (t < H) {
        const int h = t;
        float q_ = 0.f, k_ = 0.f, v_ = 0.f, t_ = 0.f;
        for (int j = 0; j < H; j++) {
            float cj = cls[j];
            q_ += cj * Wq[j * H + h];
            k_ += cj * Wk[j * H + h];
            v_ += cj * Wv[j * H + h];
            t_ += cj * Wt[j * H + h];
        }
        qv[h] = q_; kcls[h] = k_; vcls[h] = v_; tv[h] = t_;
    }
    __syncthreads();
    if (t < H) {
        const int h = t;
        float g_ = 0.f;
        for (int j = 0; j < H; j++) g_ += Wk[h * H + j] * qv[j];
        gg[h] = g_;
        for (int i = 0; i < I_DIM; i++) {
            float a = 0.f;
            for (int j = 0; j < H; j++) a += W1[i * H + j] * Wv[j * H + h];
            WV[i][h] = a;
        }
    }
    __syncthreads();
    if (t < I_DIM) {
        float a = 0.f;
        for (int j = 0; j < H; j++) a += W1[t * H + j] * gg[j];
        cst[t] = a / sdev * rs32;
    }
    if (t < I_DIM * 2) {
        const int i = t >> 1, o = t & 1;
        float a = 0.f;
        for (int j = 0; j < H; j++) a += WV[i][j] * W2[j * 2 + o];
        cst[10 + i * 2 + o] = a / sdev;
    }
    __syncthreads();
    if (t == 0) {
        float csum = 0.f;
        for (int i = 0; i < I_DIM; i++) csum += cst[i];
        cst[8] = (float)(-mu) * csum;
        float c2 = 0.f;
        for (int j = 0; j < H; j++) c2 += qv[j] * kcls[j];
        cst[9] = c2 * rs32;
        float m00 = 0.f, m01 = 0.f;
        for (int i = 0; i < I_DIM; i++) { m00 += cst[10 + i * 2]; m01 += cst[10 + i * 2 + 1]; }
        cst[26] = (float)(-mu) * m00;
        cst[27] = (float)(-mu) * m01;
        float vw0 = 0.f, vw1 = 0.f, tw0 = 0.f, tw1 = 0.f;
        for (int j = 0; j < H; j++) {
            vw0 += vcls[j] * W2[j * 2];     vw1 += vcls[j] * W2[j * 2 + 1];
            tw0 += tv[j]   * W2[j * 2];     tw1 += tv[j]   * W2[j * 2 + 1];
        }
        cst[28] = vw0; cst[29] = vw1; cst[30] = tw0; cst[31] = tw1;
    }
    __syncthreads();
}

// =================== Cooperative single-kernel path ===================
__global__ __launch_bounds__(256, 2) void fused_all(
    const float* __restrict__ X, const int* __restrict__ y,
    const float* __restrict__ W1, const float* __restrict__ cls,
    const float* __restrict__ Wq, const float* __restrict__ Wk,
    const float* __restrict__ Wv, const float* __restrict__ Wt,
    const float* __restrict__ W2, float* __restrict__ out,
    double* __restrict__ ws)
{
    cg::grid_group grid = cg::this_grid();
    const int t = threadIdx.x, b = blockIdx.x;
    const int lane = t & 63, wid = t >> 6;

    // ---- Phase A: load my 4 rows into registers + sum/sumsq partials ----
    const float4* X4 = (const float4*)X;
    const size_t base = (size_t)b * 2048;     // 4 rows = 2048 float4
    float xr[4][8];
    float s1 = 0.f, s2 = 0.f;
    #pragma unroll
    for (int r = 0; r < 4; r++) {
        float4 p0 = X4[base + r * 512 + 2 * t];
        float4 p1 = X4[base + r * 512 + 2 * t + 1];
        xr[r][0] = p0.x; xr[r][1] = p0.y; xr[r][2] = p0.z; xr[r][3] = p0.w;
        xr[r][4] = p1.x; xr[r][5] = p1.y; xr[r][6] = p1.z; xr[r][7] = p1.w;
        #pragma unroll
        for (int i = 0; i < 8; i++) { s1 += xr[r][i]; s2 += xr[r][i] * xr[r][i]; }
    }
    for (int off = 32; off; off >>= 1) {
        s1 += __shfl_down(s1, off);
        s2 += __shfl_down(s2, off);
    }
    __shared__ float ra[4], rb[4];
    if (lane == 0) { ra[wid] = s1; rb[wid] = s2; }
    __syncthreads();
    if (t == 0) {
        AST(&ws[SLOT * b],     (double)(ra[0] + ra[1] + ra[2] + ra[3]));
        AST(&ws[SLOT * b + 1], (double)(rb[0] + rb[1] + rb[2] + rb[3]));
    }
    __threadfence();
    grid.sync();

    // ---- Phase B: every block reduces the 512 partial slots + folds csts ----
    double d1 = 0.0, d2 = 0.0;
    for (int i = t; i < NBLK; i += 256) {
        d1 += ALD(&ws[SLOT * i]);
        d2 += ALD(&ws[SLOT * i + 1]);
    }
    for (int off = 32; off; off >>= 1) {
        d1 += __shfl_down(d1, off);
        d2 += __shfl_down(d2, off);
    }
    __shared__ double da[4], db[4];
    if (lane == 0) { da[wid] = d1; db[wid] = d2; }
    __syncthreads();
    const double S1 = da[0] + da[1] + da[2] + da[3];
    const double S2 = db[0] + db[1] + db[2] + db[3];
    const double mu = S1 / (double)N_TOTAL;
    const double var = (S2 - S1 * S1 / (double)N_TOTAL) / (double)(N_TOTAL - 1);
    const float sdev = (float)(sqrt(var) + 1e-7);

    __shared__ float qv[H], kcls[H], vcls[H], tv[H], gg[H], WV[I_DIM][H];
    __shared__ float cst[32];
    fold_constants(t, mu, sdev, W1, cls, Wq, Wk, Wv, Wt, W2,
                   qv, kcls, vcls, tv, gg, WV, cst);

    // ---- Phase C: attention + loss for my 4 rows (from registers) ----
    __shared__ float wmax[4];
    __shared__ float wsum[4][9];
    double lossAcc = 0.0;
    PROC_ROW(xr[0], 4 * b);
    PROC_ROW(xr[1], 4 * b + 1);
    PROC_ROW(xr[2], 4 * b + 2);
    PROC_ROW(xr[3], 4 * b + 3);
    if (t == 0) AST(&ws[WS_LOSS + SLOT * b], lossAcc);
    __threadfence();
    grid.sync();

    // ---- Phase D: block 0 reduces the 512 loss slots ----
    if (b == 0) {
        double l = 0.0;
        for (int i = t; i < NBLK; i += 256) l += ALD(&ws[WS_LOSS + SLOT * i]);
        for (int off = 32; off; off >>= 1) l += __shfl_down(l, off);
        if (lane == 0) da[wid] = l;
        __syncthreads();
        if (t == 0)
            out[0] = (float)((da[0] + da[1] + da[2] + da[3]) / (double)B_SIZE);
    }
}

// =================== Fallback multi-kernel path (round-1, passed) ===================
__global__ void reduce_sums(const float4* __restrict__ X4, double* __restrict__ ws) {
    int g = blockIdx.x * blockDim.x + threadIdx.x;
    int stride = gridDim.x * blockDim.x;
    float s1 = 0.f, s2 = 0.f;
    for (int i = g; i < N_TOTAL / 4; i += stride) {
        float4 v = X4[i];
        s1 += v.x + v.y + v.z + v.w;
        s2 += v.x * v.x + v.y * v.y + v.z * v.z + v.w * v.w;
    }
    for (int off = 32; off; off >>= 1) {
        s1 += __shfl_down(s1, off);
        s2 += __shfl_down(s2, off);
    }
    __shared__ float a1[4], a2[4];
    int lane = threadIdx.x & 63, wid = threadIdx.x >> 6;
    if (lane == 0) { a1[wid] = s1; a2[wid] = s2; }
    __syncthreads();
    if (threadIdx.x == 0) {
        atomicAdd(&ws[0], (double)(a1[0] + a1[1] + a1[2] + a1[3]));
        atomicAdd(&ws[1], (double)(a2[0] + a2[1] + a2[2] + a2[3]));
    }
}

__global__ void precompute(const double* __restrict__ sums,
                           const float* __restrict__ W1, const float* __restrict__ cls,
                           const float* __restrict__ Wq, const float* __restrict__ Wk,
                           const float* __restrict__ Wv, const float* __restrict__ Wt,
                           const float* __restrict__ W2, float* __restrict__ cstg) {
    __shared__ float qv[H], kcls[H], vcls[H], tv[H], gg[H], WV[I_DIM][H];
    __shared__ float cst[32];
    int t = threadIdx.x;
    double sum = sums[0], sumsq = sums[1];
    double mu = sum / (double)N_TOTAL;
    double var = (sumsq - sum * sum / (double)N_TOTAL) / (double)(N_TOTAL - 1);
    float sdev = (float)(sqrt(var) + 1e-7);
    fold_constants(t, mu, sdev, W1, cls, Wq, Wk, Wv, Wt, W2,
                   qv, kcls, vcls, tv, gg, WV, cst);
    if (t < 32) cstg[t] = cst[t];
}

__global__ __launch_bounds__(256) void attn_loss(const float* __restrict__ X,
                                                 const int* __restrict__ y,
                                                 const float* __restrict__ cst_g,
                                                 double* __restrict__ loss) {
    __shared__ float cst[32];
    __shared__ float wmax[4];
    __shared__ float wsum[4][9];
    int t = threadIdx.x;
    int b = blockIdx.x;
    int lane = t & 63, wid = t >> 6;
    if (t < 32) cst[t] = cst_g[t];
    __syncthreads();

    const float4* Xb = (const float4*)(X + (size_t)b * (L_SIZE * I_DIM));
    float4 p0 = Xb[t * 2], p1 = Xb[t * 2 + 1];
    float x[8] = {p0.x, p0.y, p0.z, p0.w, p1.x, p1.y, p1.z, p1.w};
    double lossAcc = 0.0;
    PROC_ROW(x, b);
    if (t == 0) atomicAdd(loss, lossAcc);
}

__global__ void finalize(const double* __restrict__ loss, float* __restrict__ out) {
    out[0] = (float)(loss[0] / (double)B_SIZE);
}

extern "C" void kernel_launch(void* const* d_in, const int* in_sizes, int n_in,
                              void* d_out, int out_size, void* d_ws, size_t ws_size,
                              hipStream_t stream) {
    const float* X   = (const float*)d_in[0];
    const int*   y   = (const int*)d_in[1];
    const float* W1  = (const float*)d_in[2];
    const float* cls = (const float*)d_in[3];
    const float* Wq  = (const float*)d_in[4];
    const float* Wk  = (const float*)d_in[5];
    const float* Wv  = (const float*)d_in[6];
    const float* Wt  = (const float*)d_in[7];
    const float* W2  = (const float*)d_in[8];
    float* out = (float*)d_out;
    double* wsd = (double*)d_ws;

    void* args[] = {(void*)&X, (void*)&y, (void*)&W1, (void*)&cls,
                    (void*)&Wq, (void*)&Wk, (void*)&Wv, (void*)&Wt,
                    (void*)&W2, (void*)&out, (void*)&wsd};
    hipError_t err = hipLaunchCooperativeKernel(
        reinterpret_cast<void*>(fused_all), dim3(NBLK), dim3(256), args, 0, stream);

    if (err != hipSuccess) {
        // Fallback: proven 4-kernel pipeline (round-1, absmax 0.0).
        float* cstg = (float*)((double*)d_ws + 4);   // 32 floats after slots? use offset 4 doubles
        hipMemsetAsync(d_ws, 0, 32, stream);          // zero wsd[0..3]
        hipLaunchKernelGGL(reduce_sums, dim3(1024), dim3(256), 0, stream,
                           (const float4*)X, wsd);
        hipLaunchKernelGGL(precompute, dim3(1), dim3(32), 0, stream,
                           wsd, W1, cls, Wq, Wk, Wv, Wt, W2, cstg);
        hipLaunchKernelGGL(attn_loss, dim3(B_SIZE), dim3(256), 0, stream,
                           X, y, cstg, wsd + 2);
        hipLaunchKernelGGL(finalize, dim3(1), dim3(1), 0, stream, wsd + 2, out);
    }
}

// Round 4
// 68.762 us; speedup vs baseline: 3.2129x; 3.2129x over previous
//
#include <hip/hip_runtime.h>

#define N_TOTAL 4194304   // 2048*256*8
#define B_SIZE  2048
#define L_SIZE  256
#define I_DIM   8
#define H       32
#define K1_BLK  256

// ws layout in doubles:
//   [16*i], [16*i+1]  i<256   : K1 per-block (sum, sumsq), 128B padded slots
//   [4096] (as 40 floats)     : raw (stats-independent) constants
//   [4128 .. 4128+2047]       : per-row loss slots (agent-scope access)
//   [6208] (as unsigned)      : done counter (zeroed by K1 each run)
#define CRAW_OFF 4096
#define LOSS_OFF 4128
#define CTR_OFF  6208

#define AST_D(p, v) __hip_atomic_store((p), (v), __ATOMIC_RELAXED, __HIP_MEMORY_SCOPE_AGENT)
#define ALD_D(p)    __hip_atomic_load((p), __ATOMIC_RELAXED, __HIP_MEMORY_SCOPE_AGENT)

// ================= K1: X pass (stats partials) + raw constant fold =================
__global__ __launch_bounds__(256) void k1_stats(
    const float4* __restrict__ X4,
    const float* __restrict__ W1, const float* __restrict__ cls,
    const float* __restrict__ Wq, const float* __restrict__ Wk,
    const float* __restrict__ Wv, const float* __restrict__ Wt,
    const float* __restrict__ W2, double* __restrict__ dws)
{
    const int t = threadIdx.x, b = blockIdx.x;
    const int lane = t & 63, wid = t >> 6;
    const int g = b * 256 + t;              // 65536 threads, 16 float4 each

    float s1 = 0.f, s2 = 0.f;
    #pragma unroll
    for (int i = 0; i < 16; i++) {
        float4 v = X4[g + i * 65536];
        s1 += v.x + v.y + v.z + v.w;
        s2 += v.x * v.x + v.y * v.y + v.z * v.z + v.w * v.w;
    }
    for (int off = 32; off; off >>= 1) {
        s1 += __shfl_down(s1, off);
        s2 += __shfl_down(s2, off);
    }
    __shared__ float a1[4], a2[4];
    if (lane == 0) { a1[wid] = s1; a2[wid] = s2; }
    __syncthreads();
    if (t == 0) {
        dws[16 * b]     = (double)(a1[0] + a1[1] + a1[2] + a1[3]);
        dws[16 * b + 1] = (double)(a2[0] + a2[1] + a2[2] + a2[3]);
    }

    // ---- block 0: stats-independent raw constants + counter zero ----
    if (b == 0) {
        __shared__ float qv[H], kcls[H], vcls[H], tv[H], gg[H], WV[I_DIM][H];
        const float rs32 = 0.17677669529663687f;  // 1/sqrt(32)
        float* craw = (float*)(dws + CRAW_OFF);
        if (t < H) {
            const int h = t;
            float q_ = 0.f, k_ = 0.f, v_ = 0.f, t_ = 0.f;
            for (int j = 0; j < H; j++) {
                float cj = cls[j];
                q_ += cj * Wq[j * H + h];
                k_ += cj * Wk[j * H + h];
                v_ += cj * Wv[j * H + h];
                t_ += cj * Wt[j * H + h];
            }
            qv[h] = q_; kcls[h] = k_; vcls[h] = v_; tv[h] = t_;
        }
        __syncthreads();
        if (t < H) {
            const int h = t;
            float g_ = 0.f;
            for (int j = 0; j < H; j++) g_ += Wk[h * H + j] * qv[j];
            gg[h] = g_;
            for (int i = 0; i < I_DIM; i++) {
                float a = 0.f;
                for (int j = 0; j < H; j++) a += W1[i * H + j] * Wv[j * H + h];
                WV[i][h] = a;
            }
        }
        __syncthreads();
        if (t < I_DIM) {                       // u_raw
            float a = 0.f;
            for (int j = 0; j < H; j++) a += W1[t * H + j] * gg[j];
            craw[t] = a;
        }
        if (t < I_DIM * 2) {                   // M_raw
            const int i = t >> 1, o = t & 1;
            float a = 0.f;
            for (int j = 0; j < H; j++) a += WV[i][j] * W2[j * 2 + o];
            craw[10 + i * 2 + o] = a;
        }
        if (t == 0) {
            float c2 = 0.f;
            for (int j = 0; j < H; j++) c2 += qv[j] * kcls[j];
            craw[9] = c2 * rs32;
            float vw0 = 0.f, vw1 = 0.f, tw0 = 0.f, tw1 = 0.f;
            for (int j = 0; j < H; j++) {
                vw0 += vcls[j] * W2[j * 2];     vw1 += vcls[j] * W2[j * 2 + 1];
                tw0 += tv[j]   * W2[j * 2];     tw1 += tv[j]   * W2[j * 2 + 1];
            }
            craw[28] = vw0; craw[29] = vw1; craw[30] = tw0; craw[31] = tw1;
            unsigned* ctr = (unsigned*)(dws + CTR_OFF);
            __hip_atomic_store(ctr, 0u, __ATOMIC_RELAXED, __HIP_MEMORY_SCOPE_AGENT);
        }
    }
}

// ================= K2: per-row attention + loss; last block finalizes =================
__global__ __launch_bounds__(256) void k2_attn(
    const float* __restrict__ X, const int* __restrict__ y,
    double* __restrict__ dws, float* __restrict__ out)
{
    const int t = threadIdx.x, b = blockIdx.x;
    const int lane = t & 63, wid = t >> 6;

    // ---- load my row into registers ----
    const float4* Xb = (const float4*)(X + (size_t)b * (L_SIZE * I_DIM));
    float4 p0 = Xb[2 * t], p1 = Xb[2 * t + 1];
    float x[8] = {p0.x, p0.y, p0.z, p0.w, p1.x, p1.y, p1.z, p1.w};

    // ---- redundant stats reduce: 256 padded slots ----
    double d1 = dws[16 * t], d2 = dws[16 * t + 1];
    for (int off = 32; off; off >>= 1) {
        d1 += __shfl_down(d1, off);
        d2 += __shfl_down(d2, off);
    }
    __shared__ double da[4], db[4];
    if (lane == 0) { da[wid] = d1; db[wid] = d2; }
    __syncthreads();

    __shared__ float sNegMu, sSdev;
    if (t == 0) {
        double S1 = da[0] + da[1] + da[2] + da[3];
        double S2 = db[0] + db[1] + db[2] + db[3];
        double mu = S1 / (double)N_TOTAL;
        double var = (S2 - S1 * S1 / (double)N_TOTAL) / (double)(N_TOTAL - 1);
        sSdev = (float)(sqrt(var) + 1e-7);
        sNegMu = (float)(-mu);
    }
    __syncthreads();

    // ---- scale raw constants ----
    __shared__ float cst[32];
    const float* craw = (const float*)(dws + CRAW_OFF);
    const float rs32 = 0.17677669529663687f;
    if (t < 32) {
        const float sdev = sSdev, negmu = sNegMu;
        if (t < 8) {
            cst[t] = craw[t] / sdev * rs32;
        } else if (t == 8) {
            float cs = 0.f;
            for (int i = 0; i < 8; i++) cs += craw[i] / sdev * rs32;
            cst[8] = negmu * cs;
        } else if (t == 9) {
            cst[9] = craw[9];
        } else if (t < 26) {
            cst[t] = craw[t] / sdev;
        } else if (t == 26) {
            float m0 = 0.f;
            for (int i = 0; i < 8; i++) m0 += craw[10 + 2 * i] / sdev;
            cst[26] = negmu * m0;
        } else if (t == 27) {
            float m1 = 0.f;
            for (int i = 0; i < 8; i++) m1 += craw[11 + 2 * i] / sdev;
            cst[27] = negmu * m1;
        } else {
            cst[t] = craw[t];
        }
    }
    __syncthreads();

    // ---- score, softmax, logits, loss ----
    float sc = cst[8];
    #pragma unroll
    for (int i = 0; i < 8; i++) sc += x[i] * cst[i];

    float m = sc;
    for (int off = 32; off; off >>= 1) m = fmaxf(m, __shfl_down(m, off));
    __shared__ float wmax[4];
    __shared__ float wsum[4][9];
    if (lane == 0) wmax[wid] = m;
    __syncthreads();
    m = fmaxf(fmaxf(wmax[0], wmax[1]), fmaxf(wmax[2], wmax[3]));
    m = fmaxf(m, cst[9]);

    float e = expf(sc - m);
    float v[9];
    v[0] = e;
    #pragma unroll
    for (int i = 0; i < 8; i++) v[i + 1] = e * x[i];
    for (int off = 32; off; off >>= 1) {
        #pragma unroll
        for (int j = 0; j < 9; j++) v[j] += __shfl_down(v[j], off);
    }
    if (lane == 0) {
        #pragma unroll
        for (int j = 0; j < 9; j++) wsum[wid][j] = v[j];
    }
    __syncthreads();

    __shared__ int lastFlag;
    if (t == 0) {
        float se = wsum[0][0] + wsum[1][0] + wsum[2][0] + wsum[3][0];
        float ecls = expf(cst[9] - m);
        float inv = 1.f / (se + ecls);
        float S256 = ecls * inv;
        float z[2];
        #pragma unroll
        for (int o = 0; o < 2; o++) {
            float a = 0.f;
            #pragma unroll
            for (int i = 0; i < 8; i++) {
                float wi = (wsum[0][i + 1] + wsum[1][i + 1] +
                            wsum[2][i + 1] + wsum[3][i + 1]) * inv;
                a += wi * cst[10 + i * 2 + o];
            }
            z[o] = a + (1.f - S256) * cst[26 + o] + S256 * cst[28 + o] + cst[30 + o];
        }
        float zm = fmaxf(z[0], z[1]);
        float lse = zm + logf(expf(z[0] - zm) + expf(z[1] - zm));
        int yb = y[b];
        AST_D(&dws[LOSS_OFF + b], (double)(lse - z[yb]));
        unsigned* ctr = (unsigned*)(dws + CTR_OFF);
        unsigned old = __hip_atomic_fetch_add(ctr, 1u, __ATOMIC_ACQ_REL,
                                              __HIP_MEMORY_SCOPE_AGENT);
        lastFlag = (old == (unsigned)(B_SIZE - 1));
    }
    __syncthreads();

    // ---- last-finishing block reduces all 2048 losses ----
    if (lastFlag) {
        double l = 0.0;
        for (int i = t; i < B_SIZE; i += 256) l += ALD_D(&dws[LOSS_OFF + i]);
        for (int off = 32; off; off >>= 1) l += __shfl_down(l, off);
        if (lane == 0) da[wid] = l;
        __syncthreads();
        if (t == 0)
            out[0] = (float)((da[0] + da[1] + da[2] + da[3]) / (double)B_SIZE);
    }
}

extern "C" void kernel_launch(void* const* d_in, const int* in_sizes, int n_in,
                              void* d_out, int out_size, void* d_ws, size_t ws_size,
                              hipStream_t stream) {
    const float* X   = (const float*)d_in[0];
    const int*   y   = (const int*)d_in[1];
    const float* W1  = (const float*)d_in[2];
    const float* cls = (const float*)d_in[3];
    const float* Wq  = (const float*)d_in[4];
    const float* Wk  = (const float*)d_in[5];
    const float* Wv  = (const float*)d_in[6];
    const float* Wt  = (const float*)d_in[7];
    const float* W2  = (const float*)d_in[8];
    float* out = (float*)d_out;
    double* dws = (double*)d_ws;

    hipLaunchKernelGGL(k1_stats, dim3(K1_BLK), dim3(256), 0, stream,
                       (const float4*)X, W1, cls, Wq, Wk, Wv, Wt, W2, dws);
    hipLaunchKernelGGL(k2_attn, dim3(B_SIZE), dim3(256), 0, stream,
                       X, y, dws, out);
}

// Round 5
// 26.545 us; speedup vs baseline: 8.3227x; 2.5904x over previous
//
#include <hip/hip_runtime.h>

#define N_TOTAL 4194304   // 2048*256*8
#define B_SIZE  2048
#define L_SIZE  256
#define I_DIM   8
#define H       32
#define K1_BLK  256       // K1: 256 blocks x 1024 threads

// ws layout in doubles:
//   [16*i], [16*i+1]  i<256   : K1 per-block (sum, sumsq), 128B padded slots
//   [4096] (as 32 floats)     : raw (stats-independent) constants
//   [4128 .. 4128+2047]       : per-row loss slots
#define CRAW_OFF 4096
#define LOSS_OFF 4128

// ================= K1: X pass (stats partials) + raw constant fold =================
__global__ __launch_bounds__(1024) void k1_stats(
    const float4* __restrict__ X4,
    const float* __restrict__ W1, const float* __restrict__ cls,
    const float* __restrict__ Wq, const float* __restrict__ Wk,
    const float* __restrict__ Wv, const float* __restrict__ Wt,
    const float* __restrict__ W2, double* __restrict__ dws)
{
    const int t = threadIdx.x, b = blockIdx.x;
    const int lane = t & 63, wid = t >> 6;      // 16 waves
    const int g = b * 1024 + t;                 // 262144 threads, 4 float4 each

    float s1 = 0.f, s2 = 0.f;
    #pragma unroll
    for (int i = 0; i < 4; i++) {
        float4 v = X4[g + i * 262144];
        s1 += v.x + v.y + v.z + v.w;
        s2 += v.x * v.x + v.y * v.y + v.z * v.z + v.w * v.w;
    }
    for (int off = 32; off; off >>= 1) {
        s1 += __shfl_down(s1, off);
        s2 += __shfl_down(s2, off);
    }
    __shared__ float a1[16], a2[16];
    if (lane == 0) { a1[wid] = s1; a2[wid] = s2; }
    __syncthreads();
    if (t == 0) {
        float r1 = 0.f, r2 = 0.f;
        #pragma unroll
        for (int i = 0; i < 16; i++) { r1 += a1[i]; r2 += a2[i]; }
        dws[16 * b]     = (double)r1;
        dws[16 * b + 1] = (double)r2;
    }

    // ---- block 0: stats-independent raw constants ----
    if (b == 0) {
        __shared__ float qv[H], kcls[H], vcls[H], tv[H], gg[H], WV[I_DIM][H];
        const float rs32 = 0.17677669529663687f;  // 1/sqrt(32)
        float* craw = (float*)(dws + CRAW_OFF);
        if (t < H) {
            const int h = t;
            float q_ = 0.f, k_ = 0.f, v_ = 0.f, t_ = 0.f;
            for (int j = 0; j < H; j++) {
                float cj = cls[j];
                q_ += cj * Wq[j * H + h];
                k_ += cj * Wk[j * H + h];
                v_ += cj * Wv[j * H + h];
                t_ += cj * Wt[j * H + h];
            }
            qv[h] = q_; kcls[h] = k_; vcls[h] = v_; tv[h] = t_;
        }
        __syncthreads();
        if (t < H) {
            const int h = t;
            float g_ = 0.f;
            for (int j = 0; j < H; j++) g_ += Wk[h * H + j] * qv[j];
            gg[h] = g_;
            for (int i = 0; i < I_DIM; i++) {
                float a = 0.f;
                for (int j = 0; j < H; j++) a += W1[i * H + j] * Wv[j * H + h];
                WV[i][h] = a;
            }
        }
        __syncthreads();
        if (t < I_DIM) {                       // u_raw
            float a = 0.f;
            for (int j = 0; j < H; j++) a += W1[t * H + j] * gg[j];
            craw[t] = a;
        }
        if (t < I_DIM * 2) {                   // M_raw
            const int i = t >> 1, o = t & 1;
            float a = 0.f;
            for (int j = 0; j < H; j++) a += WV[i][j] * W2[j * 2 + o];
            craw[10 + i * 2 + o] = a;
        }
        if (t == 0) {
            float c2 = 0.f;
            for (int j = 0; j < H; j++) c2 += qv[j] * kcls[j];
            craw[9] = c2 * rs32;
            float vw0 = 0.f, vw1 = 0.f, tw0 = 0.f, tw1 = 0.f;
            for (int j = 0; j < H; j++) {
                vw0 += vcls[j] * W2[j * 2];     vw1 += vcls[j] * W2[j * 2 + 1];
                tw0 += tv[j]   * W2[j * 2];     tw1 += tv[j]   * W2[j * 2 + 1];
            }
            craw[28] = vw0; craw[29] = vw1; craw[30] = tw0; craw[31] = tw1;
        }
    }
}

// ================= K2: per-row attention + loss (no atomics) =================
__global__ __launch_bounds__(256) void k2_attn(
    const float* __restrict__ X, const int* __restrict__ y,
    double* __restrict__ dws)
{
    const int t = threadIdx.x, b = blockIdx.x;
    const int lane = t & 63, wid = t >> 6;

    // ---- load my row into registers ----
    const float4* Xb = (const float4*)(X + (size_t)b * (L_SIZE * I_DIM));
    float4 p0 = Xb[2 * t], p1 = Xb[2 * t + 1];
    float x[8] = {p0.x, p0.y, p0.z, p0.w, p1.x, p1.y, p1.z, p1.w};

    // ---- redundant stats reduce: 256 padded slots ----
    double d1 = dws[16 * t], d2 = dws[16 * t + 1];
    for (int off = 32; off; off >>= 1) {
        d1 += __shfl_down(d1, off);
        d2 += __shfl_down(d2, off);
    }
    __shared__ double da[4], db[4];
    if (lane == 0) { da[wid] = d1; db[wid] = d2; }
    __syncthreads();

    __shared__ float sNegMu, sSdev;
    if (t == 0) {
        double S1 = da[0] + da[1] + da[2] + da[3];
        double S2 = db[0] + db[1] + db[2] + db[3];
        double mu = S1 / (double)N_TOTAL;
        double var = (S2 - S1 * S1 / (double)N_TOTAL) / (double)(N_TOTAL - 1);
        sSdev = (float)(sqrt(var) + 1e-7);
        sNegMu = (float)(-mu);
    }
    __syncthreads();

    // ---- scale raw constants ----
    __shared__ float cst[32];
    const float* craw = (const float*)(dws + CRAW_OFF);
    const float rs32 = 0.17677669529663687f;
    if (t < 32) {
        const float sdev = sSdev, negmu = sNegMu;
        if (t < 8) {
            cst[t] = craw[t] / sdev * rs32;
        } else if (t == 8) {
            float cs = 0.f;
            for (int i = 0; i < 8; i++) cs += craw[i] / sdev * rs32;
            cst[8] = negmu * cs;
        } else if (t == 9) {
            cst[9] = craw[9];
        } else if (t < 26) {
            cst[t] = craw[t] / sdev;
        } else if (t == 26) {
            float m0 = 0.f;
            for (int i = 0; i < 8; i++) m0 += craw[10 + 2 * i] / sdev;
            cst[26] = negmu * m0;
        } else if (t == 27) {
            float m1 = 0.f;
            for (int i = 0; i < 8; i++) m1 += craw[11 + 2 * i] / sdev;
            cst[27] = negmu * m1;
        } else {
            cst[t] = craw[t];
        }
    }
    __syncthreads();

    // ---- score, softmax, logits, loss ----
    float sc = cst[8];
    #pragma unroll
    for (int i = 0; i < 8; i++) sc += x[i] * cst[i];

    float m = sc;
    for (int off = 32; off; off >>= 1) m = fmaxf(m, __shfl_down(m, off));
    __shared__ float wmax[4];
    __shared__ float wsum[4][9];
    if (lane == 0) wmax[wid] = m;
    __syncthreads();
    m = fmaxf(fmaxf(wmax[0], wmax[1]), fmaxf(wmax[2], wmax[3]));
    m = fmaxf(m, cst[9]);

    float e = expf(sc - m);
    float v[9];
    v[0] = e;
    #pragma unroll
    for (int i = 0; i < 8; i++) v[i + 1] = e * x[i];
    for (int off = 32; off; off >>= 1) {
        #pragma unroll
        for (int j = 0; j < 9; j++) v[j] += __shfl_down(v[j], off);
    }
    if (lane == 0) {
        #pragma unroll
        for (int j = 0; j < 9; j++) wsum[wid][j] = v[j];
    }
    __syncthreads();

    if (t == 0) {
        float se = wsum[0][0] + wsum[1][0] + wsum[2][0] + wsum[3][0];
        float ecls = expf(cst[9] - m);
        float inv = 1.f / (se + ecls);
        float S256 = ecls * inv;
        float z[2];
        #pragma unroll
        for (int o = 0; o < 2; o++) {
            float a = 0.f;
            #pragma unroll
            for (int i = 0; i < 8; i++) {
                float wi = (wsum[0][i + 1] + wsum[1][i + 1] +
                            wsum[2][i + 1] + wsum[3][i + 1]) * inv;
                a += wi * cst[10 + i * 2 + o];
            }
            z[o] = a + (1.f - S256) * cst[26 + o] + S256 * cst[28 + o] + cst[30 + o];
        }
        float zm = fmaxf(z[0], z[1]);
        float lse = zm + logf(expf(z[0] - zm) + expf(z[1] - zm));
        int yb = y[b];
        dws[LOSS_OFF + b] = (double)(lse - z[yb]);
    }
}

// ================= K3: reduce 2048 losses -> out =================
__global__ __launch_bounds__(256) void k3_finalize(
    const double* __restrict__ dws, float* __restrict__ out)
{
    const int t = threadIdx.x;
    const int lane = t & 63, wid = t >> 6;
    double l = 0.0;
    for (int i = t; i < B_SIZE; i += 256) l += dws[LOSS_OFF + i];
    for (int off = 32; off; off >>= 1) l += __shfl_down(l, off);
    __shared__ double da[4];
    if (lane == 0) da[wid] = l;
    __syncthreads();
    if (t == 0)
        out[0] = (float)((da[0] + da[1] + da[2] + da[3]) / (double)B_SIZE);
}

extern "C" void kernel_launch(void* const* d_in, const int* in_sizes, int n_in,
                              void* d_out, int out_size, void* d_ws, size_t ws_size,
                              hipStream_t stream) {
    const float* X   = (const float*)d_in[0];
    const int*   y   = (const int*)d_in[1];
    const float* W1  = (const float*)d_in[2];
    const float* cls = (const float*)d_in[3];
    const float* Wq  = (const float*)d_in[4];
    const float* Wk  = (const float*)d_in[5];
    const float* Wv  = (const float*)d_in[6];
    const float* Wt  = (const float*)d_in[7];
    const float* W2  = (const float*)d_in[8];
    float* out = (float*)d_out;
    double* dws = (double*)d_ws;

    hipLaunchKernelGGL(k1_stats, dim3(K1_BLK), dim3(1024), 0, stream,
                       (const float4*)X, W1, cls, Wq, Wk, Wv, Wt, W2, dws);
    hipLaunchKernelGGL(k2_attn, dim3(B_SIZE), dim3(256), 0, stream, X, y, dws);
    hipLaunchKernelGGL(k3_finalize, dim3(1), dim3(256), 0, stream, dws, out);
}

// Round 6
// 21.717 us; speedup vs baseline: 10.1729x; 1.2223x over previous
//
#include <hip/hip_runtime.h>

#define N_TOTAL 4194304   // 2048*256*8
#define B_SIZE  2048
#define L_SIZE  256
#define I_DIM   8
#define H       32
#define K1_BLK  256       // K1: 256 blocks x 1024 threads

// ws layout in doubles:
//   [16*i], [16*i+1]  i<256 : K1 per-block (sum, sumsq), 128B padded slots
//   [4096 .. 4111]          : 32 floats of raw (stats-independent) constants
//   [4112]                  : u64 packed accumulator (low 56b: fixed loss, high 8b: arrivals)
#define CRAW_OFF 4096
#define ACC_OFF  4112
#define FIXSCALE 4294967296.0   // 2^32
#define MASK56   0x00FFFFFFFFFFFFFFull

// ================= K1: X pass (stats partials) + raw constant fold =================
__global__ __launch_bounds__(1024) void k1_stats(
    const float4* __restrict__ X4,
    const float* __restrict__ W1, const float* __restrict__ cls,
    const float* __restrict__ Wq, const float* __restrict__ Wk,
    const float* __restrict__ Wv, const float* __restrict__ Wt,
    const float* __restrict__ W2, double* __restrict__ dws)
{
    const int t = threadIdx.x, b = blockIdx.x;
    const int lane = t & 63, wid = t >> 6;      // 16 waves
    const int g = b * 1024 + t;                 // 262144 threads, 4 float4 each

    float s1 = 0.f, s2 = 0.f;
    #pragma unroll
    for (int i = 0; i < 4; i++) {
        float4 v = X4[g + i * 262144];
        s1 += v.x + v.y + v.z + v.w;
        s2 += v.x * v.x + v.y * v.y + v.z * v.z + v.w * v.w;
    }
    for (int off = 32; off; off >>= 1) {
        s1 += __shfl_down(s1, off);
        s2 += __shfl_down(s2, off);
    }
    __shared__ float a1[16], a2[16];
    if (lane == 0) { a1[wid] = s1; a2[wid] = s2; }
    __syncthreads();
    if (t == 0) {
        float r1 = 0.f, r2 = 0.f;
        #pragma unroll
        for (int i = 0; i < 16; i++) { r1 += a1[i]; r2 += a2[i]; }
        dws[16 * b]     = (double)r1;
        dws[16 * b + 1] = (double)r2;
    }

    // ---- block 0: stats-independent raw constants + accumulator zero ----
    if (b == 0) {
        __shared__ float qv[H], kcls[H], vcls[H], tv[H], gg[H], WV[I_DIM][H];
        const float rs32 = 0.17677669529663687f;  // 1/sqrt(32)
        float* craw = (float*)(dws + CRAW_OFF);
        if (t < H) {
            const int h = t;
            float q_ = 0.f, k_ = 0.f, v_ = 0.f, t_ = 0.f;
            for (int j = 0; j < H; j++) {
                float cj = cls[j];
                q_ += cj * Wq[j * H + h];
                k_ += cj * Wk[j * H + h];
                v_ += cj * Wv[j * H + h];
                t_ += cj * Wt[j * H + h];
            }
            qv[h] = q_; kcls[h] = k_; vcls[h] = v_; tv[h] = t_;
        }
        __syncthreads();
        if (t < H) {
            const int h = t;
            float g_ = 0.f;
            for (int j = 0; j < H; j++) g_ += Wk[h * H + j] * qv[j];
            gg[h] = g_;
            for (int i = 0; i < I_DIM; i++) {
                float a = 0.f;
                for (int j = 0; j < H; j++) a += W1[i * H + j] * Wv[j * H + h];
                WV[i][h] = a;
            }
        }
        __syncthreads();
        if (t < I_DIM) {                       // u_raw
            float a = 0.f;
            for (int j = 0; j < H; j++) a += W1[t * H + j] * gg[j];
            craw[t] = a;
        }
        if (t < I_DIM * 2) {                   // M_raw
            const int i = t >> 1, o = t & 1;
            float a = 0.f;
            for (int j = 0; j < H; j++) a += WV[i][j] * W2[j * 2 + o];
            craw[10 + i * 2 + o] = a;
        }
        if (t == 0) {
            float c2 = 0.f;
            for (int j = 0; j < H; j++) c2 += qv[j] * kcls[j];
            craw[9] = c2 * rs32;
            float vw0 = 0.f, vw1 = 0.f, tw0 = 0.f, tw1 = 0.f;
            for (int j = 0; j < H; j++) {
                vw0 += vcls[j] * W2[j * 2];     vw1 += vcls[j] * W2[j * 2 + 1];
                tw0 += tv[j]   * W2[j * 2];     tw1 += tv[j]   * W2[j * 2 + 1];
            }
            craw[28] = vw0; craw[29] = vw1; craw[30] = tw0; craw[31] = tw1;
            *(unsigned long long*)(dws + ACC_OFF) = 0ull;   // reset packed accumulator
        }
    }
}

// ================= K2: wave-per-row attention + packed-atomic finalize =================
__global__ __launch_bounds__(512) void k2_attn(
    const float* __restrict__ X, const int* __restrict__ y,
    double* __restrict__ dws, float* __restrict__ out)
{
    const int t = threadIdx.x, b = blockIdx.x;
    const int lane = t & 63, w = t >> 6;       // 8 waves, one row each

    __shared__ double da[4], db[4];
    __shared__ float cst[32];
    __shared__ double wloss[8];

    // ---- stats reduce (waves 0-3 over the 256 padded slots) ----
    if (t < 256) {
        double d1 = dws[16 * t], d2 = dws[16 * t + 1];
        for (int off = 32; off; off >>= 1) {
            d1 += __shfl_down(d1, off);
            d2 += __shfl_down(d2, off);
        }
        if (lane == 0) { da[w] = d1; db[w] = d2; }
    }
    __syncthreads();
    const double S1 = da[0] + da[1] + da[2] + da[3];
    const double S2 = db[0] + db[1] + db[2] + db[3];
    const double mu = S1 / (double)N_TOTAL;
    const double var = (S2 - S1 * S1 / (double)N_TOTAL) / (double)(N_TOTAL - 1);
    const float sdev = (float)(sqrt(var) + 1e-7);
    const float negmu = (float)(-mu);

    // ---- scale raw constants into LDS cst[32] ----
    const float* craw = (const float*)(dws + CRAW_OFF);
    const float rs32 = 0.17677669529663687f;
    if (t < 32) {
        if (t < 8) {
            cst[t] = craw[t] / sdev * rs32;
        } else if (t == 8) {
            float cs = 0.f;
            for (int i = 0; i < 8; i++) cs += craw[i] / sdev * rs32;
            cst[8] = negmu * cs;
        } else if (t == 9) {
            cst[9] = craw[9];
        } else if (t < 26) {
            cst[t] = craw[t] / sdev;
        } else if (t == 26) {
            float m0 = 0.f;
            for (int i = 0; i < 8; i++) m0 += craw[10 + 2 * i] / sdev;
            cst[26] = negmu * m0;
        } else if (t == 27) {
            float m1 = 0.f;
            for (int i = 0; i < 8; i++) m1 += craw[11 + 2 * i] / sdev;
            cst[27] = negmu * m1;
        } else {
            cst[t] = craw[t];
        }
    }
    __syncthreads();

    // ---- one row per wave: r = b*8 + w, lane handles positions lane+64j ----
    const int r = b * 8 + w;
    const float4* Xb = (const float4*)(X + (size_t)r * (L_SIZE * I_DIM));
    float x[4][8];
    float sc[4];
    const float c8 = cst[8];
    float u0 = cst[0], u1 = cst[1], u2 = cst[2], u3 = cst[3];
    float u4 = cst[4], u5 = cst[5], u6 = cst[6], u7 = cst[7];
    #pragma unroll
    for (int j = 0; j < 4; j++) {
        const int p = 64 * j + lane;
        float4 p0 = Xb[2 * p], p1 = Xb[2 * p + 1];
        x[j][0] = p0.x; x[j][1] = p0.y; x[j][2] = p0.z; x[j][3] = p0.w;
        x[j][4] = p1.x; x[j][5] = p1.y; x[j][6] = p1.z; x[j][7] = p1.w;
        sc[j] = c8 + x[j][0] * u0 + x[j][1] * u1 + x[j][2] * u2 + x[j][3] * u3
                   + x[j][4] * u4 + x[j][5] * u5 + x[j][6] * u6 + x[j][7] * u7;
    }

    // wave max (include cls score)
    float m = fmaxf(fmaxf(sc[0], sc[1]), fmaxf(sc[2], sc[3]));
    for (int off = 32; off; off >>= 1) m = fmaxf(m, __shfl_xor(m, off));
    m = fmaxf(m, cst[9]);

    // weighted partial sums over my 4 positions
    float v[9];
    #pragma unroll
    for (int j2 = 0; j2 < 9; j2++) v[j2] = 0.f;
    #pragma unroll
    for (int j = 0; j < 4; j++) {
        float e = expf(sc[j] - m);
        v[0] += e;
        #pragma unroll
        for (int i = 0; i < 8; i++) v[i + 1] += e * x[j][i];
    }
    for (int off = 32; off; off >>= 1) {
        #pragma unroll
        for (int j2 = 0; j2 < 9; j2++) v[j2] += __shfl_down(v[j2], off);
    }

    if (lane == 0) {
        float se = v[0];
        float ecls = expf(cst[9] - m);
        float inv = 1.f / (se + ecls);
        float S256 = ecls * inv;
        float z[2];
        #pragma unroll
        for (int o = 0; o < 2; o++) {
            float a = 0.f;
            #pragma unroll
            for (int i = 0; i < 8; i++)
                a += (v[i + 1] * inv) * cst[10 + i * 2 + o];
            z[o] = a + (1.f - S256) * cst[26 + o] + S256 * cst[28 + o] + cst[30 + o];
        }
        float zm = fmaxf(z[0], z[1]);
        float lse = zm + logf(expf(z[0] - zm) + expf(z[1] - zm));
        int yb = y[r];
        wloss[w] = (double)(lse - z[yb]);
    }
    __syncthreads();

    // ---- one packed relaxed RMW per block; carrier of both sum and arrival ----
    if (t == 0) {
        double blockloss = 0.0;
        #pragma unroll
        for (int i = 0; i < 8; i++) blockloss += wloss[i];
        unsigned long long fixed =
            (unsigned long long)(blockloss * FIXSCALE + 0.5);
        unsigned long long* acc = (unsigned long long*)(dws + ACC_OFF);
        unsigned long long old = __hip_atomic_fetch_add(
            acc, fixed + (1ull << 56), __ATOMIC_RELAXED, __HIP_MEMORY_SCOPE_AGENT);
        if ((old >> 56) == 255ull) {   // I am the last of 256 blocks
            unsigned long long total = ((old & MASK56) + fixed) & MASK56;
            out[0] = (float)((double)total / FIXSCALE / (double)B_SIZE);
        }
    }
}

extern "C" void kernel_launch(void* const* d_in, const int* in_sizes, int n_in,
                              void* d_out, int out_size, void* d_ws, size_t ws_size,
                              hipStream_t stream) {
    const float* X   = (const float*)d_in[0];
    const int*   y   = (const int*)d_in[1];
    const float* W1  = (const float*)d_in[2];
    const float* cls = (const float*)d_in[3];
    const float* Wq  = (const float*)d_in[4];
    const float* Wk  = (const float*)d_in[5];
    const float* Wv  = (const float*)d_in[6];
    const float* Wt  = (const float*)d_in[7];
    const float* W2  = (const float*)d_in[8];
    float* out = (float*)d_out;
    double* dws = (double*)d_ws;

    hipLaunchKernelGGL(k1_stats, dim3(K1_BLK), dim3(1024), 0, stream,
                       (const float4*)X, W1, cls, Wq, Wk, Wv, Wt, W2, dws);
    hipLaunchKernelGGL(k2_attn, dim3(K1_BLK), dim3(512), 0, stream,
                       X, y, dws, out);
}